// Round 1
// baseline (753.176 us; speedup 1.0000x reference)
//
#include <hip/hip_runtime.h>
#include <cstdint>
#include <cstddef>

// Problem constants (from reference)
#define AUDIO_DIM 512
#define TEXT_DIM  768
#define HIDDEN    512
#define BATCH     8
#define ALEN      2048
#define TLEN      512

// ---------------------------------------------------------------------------
// Generic tiled fp32 GEMM with bias: C[M,N] = A[M,K] @ W[K,N] + bias[N]
// 64x64 block tile, BK=32, 256 threads, 4x4 micro-tile per thread.
// All problem dims are multiples of the tiles -> no bounds checks.
// ---------------------------------------------------------------------------
#define BM 64
#define BN 64
#define BK 32
#define LSTR 68   // BM+4 pad: keeps 16B alignment for b128 reads, breaks write conflicts

__global__ __launch_bounds__(256) void gemm_bias_kernel(
    const float* __restrict__ A, const float* __restrict__ W,
    const float* __restrict__ bias, float* __restrict__ C,
    int M, int N, int K)
{
    __shared__ float As[BK * LSTR];   // As[kk][m]
    __shared__ float Ws[BK * LSTR];   // Ws[kk][n]
    const int tid = threadIdx.x;
    const int tx = tid & 15;          // -> 4 cols
    const int ty = tid >> 4;          // -> 4 rows
    const int m0 = blockIdx.y * BM;
    const int n0 = blockIdx.x * BN;

    float acc[4][4] = {};

    for (int k0 = 0; k0 < K; k0 += BK) {
        // Stage A tile (coalesced over k within a row), transposed into As[kk][m]
#pragma unroll
        for (int i = 0; i < 8; i++) {
            int idx = tid + i * 256;          // 0..2047
            int kk = idx & 31;
            int m  = idx >> 5;
            As[kk * LSTR + m] = A[(size_t)(m0 + m) * K + (k0 + kk)];
        }
        // Stage W tile (coalesced over n)
#pragma unroll
        for (int i = 0; i < 8; i++) {
            int idx = tid + i * 256;
            int n  = idx & 63;
            int kk = idx >> 6;
            Ws[kk * LSTR + n] = W[(size_t)(k0 + kk) * N + (n0 + n)];
        }
        __syncthreads();

#pragma unroll
        for (int kk = 0; kk < BK; kk++) {
            const float4 av = *(const float4*)&As[kk * LSTR + ty * 4];
            const float4 wv = *(const float4*)&Ws[kk * LSTR + tx * 4];
            const float a[4] = {av.x, av.y, av.z, av.w};
            const float w[4] = {wv.x, wv.y, wv.z, wv.w};
#pragma unroll
            for (int i = 0; i < 4; i++)
#pragma unroll
                for (int j = 0; j < 4; j++)
                    acc[i][j] += a[i] * w[j];
        }
        __syncthreads();
    }

    const float4 bvv = *(const float4*)&bias[n0 + tx * 4];
    const float bb[4] = {bvv.x, bvv.y, bvv.z, bvv.w};
#pragma unroll
    for (int i = 0; i < 4; i++) {
        float4 o;
        o.x = acc[i][0] + bb[0];
        o.y = acc[i][1] + bb[1];
        o.z = acc[i][2] + bb[2];
        o.w = acc[i][3] + bb[3];
        *(float4*)&C[(size_t)(m0 + ty * 4 + i) * N + (n0 + tx * 4)] = o;
    }
}

// ---------------------------------------------------------------------------
// Fused attention: per block = (batch b, 16 audio rows).
//   Phase A: load Q tile (16x512) from d_out (written by Q-GEMM) into LDS
//   Phase B: scores[r][t] = scale * q[r].k[t]  (masked -> -1e30), into LDS
//   Phase C: per-row softmax (wave-wide shuffle reduce, 4 rows per wave)
//   Phase D: out[r][h] = sum_t attn[r][t] * V[t][h], write to d_out
// LDS: 16*512*4 * 2 = 64 KB -> 2 blocks/CU.
// ---------------------------------------------------------------------------
#define TM 16

__global__ __launch_bounds__(256) void attn_kernel(
    const float* __restrict__ Kbuf,   // [B, TLEN, HIDDEN]
    const float* __restrict__ Vbuf,   // [B, TLEN, HIDDEN]
    const int*   __restrict__ mask,   // [B, TLEN]
    float* __restrict__ out)          // [B, ALEN, HIDDEN]; also holds Q on entry
{
    __shared__ float s_q[TM * HIDDEN];   // 32 KB
    __shared__ float s_s[TM * TLEN];     // 32 KB
    const int tid = threadIdx.x;
    const int b  = blockIdx.y;
    const int a0 = blockIdx.x * TM;
    const float scale = 0.044194173824159216f;  // 512^-0.5

    // ---- Phase A: load Q tile ----
    {
        const float4* Q4 = (const float4*)out;
        float4* s_q4 = (float4*)s_q;
#pragma unroll
        for (int i = 0; i < 8; i++) {
            int idx = tid + i * 256;          // 0..2047 float4s
            int r  = idx >> 7;                // /128
            int c4 = idx & 127;
            s_q4[r * 128 + c4] = Q4[((size_t)(b * ALEN + a0 + r)) * 128 + c4];
        }
    }
    __syncthreads();

    // ---- Phase B: scores ----
    {
        const int t0 = tid;
        const int t1 = tid + 256;
        const int mv0 = mask[b * TLEN + t0];
        const int mv1 = mask[b * TLEN + t1];
        const float4* K4 = (const float4*)(Kbuf + (size_t)b * TLEN * HIDDEN);
        const float4* s_q4 = (const float4*)s_q;
        float s0[TM] = {};
        float s1[TM] = {};
        for (int h4 = 0; h4 < HIDDEN / 4; h4++) {
            const float4 k0v = K4[(size_t)t0 * 128 + h4];
            const float4 k1v = K4[(size_t)t1 * 128 + h4];
#pragma unroll
            for (int r = 0; r < TM; r++) {
                const float4 qv = s_q4[r * 128 + h4];   // broadcast
                s0[r] += qv.x * k0v.x + qv.y * k0v.y + qv.z * k0v.z + qv.w * k0v.w;
                s1[r] += qv.x * k1v.x + qv.y * k1v.y + qv.z * k1v.z + qv.w * k1v.w;
            }
        }
#pragma unroll
        for (int r = 0; r < TM; r++) {
            s_s[r * TLEN + t0] = mv0 ? s0[r] * scale : -1e30f;
            s_s[r * TLEN + t1] = mv1 ? s1[r] * scale : -1e30f;
        }
    }
    __syncthreads();

    // ---- Phase C: softmax per row ----
    {
        const int wave = tid >> 6;
        const int lane = tid & 63;
#pragma unroll
        for (int rr = 0; rr < 4; rr++) {
            const int r = wave * 4 + rr;
            float p[8];
            float mx = -1e30f;
#pragma unroll
            for (int i = 0; i < 8; i++) {
                p[i] = s_s[r * TLEN + lane + i * 64];
                mx = fmaxf(mx, p[i]);
            }
#pragma unroll
            for (int off = 32; off >= 1; off >>= 1)
                mx = fmaxf(mx, __shfl_xor(mx, off));
            float sum = 0.0f;
#pragma unroll
            for (int i = 0; i < 8; i++) {
                p[i] = __expf(p[i] - mx);
                sum += p[i];
            }
#pragma unroll
            for (int off = 32; off >= 1; off >>= 1)
                sum += __shfl_xor(sum, off);
            const float inv = 1.0f / sum;
#pragma unroll
            for (int i = 0; i < 8; i++)
                s_s[r * TLEN + lane + i * 64] = p[i] * inv;
        }
    }
    __syncthreads();

    // ---- Phase D: out = attn @ V ----
    {
        const int h0 = tid;
        const int h1 = tid + 256;
        const float* Vb = Vbuf + (size_t)b * TLEN * HIDDEN;
        const float4* s_s4 = (const float4*)s_s;
        float o0[TM] = {};
        float o1[TM] = {};
        for (int t4 = 0; t4 < TLEN / 4; t4++) {
            const int t = t4 * 4;
            const float v00 = Vb[(size_t)(t + 0) * HIDDEN + h0];
            const float v01 = Vb[(size_t)(t + 1) * HIDDEN + h0];
            const float v02 = Vb[(size_t)(t + 2) * HIDDEN + h0];
            const float v03 = Vb[(size_t)(t + 3) * HIDDEN + h0];
            const float v10 = Vb[(size_t)(t + 0) * HIDDEN + h1];
            const float v11 = Vb[(size_t)(t + 1) * HIDDEN + h1];
            const float v12 = Vb[(size_t)(t + 2) * HIDDEN + h1];
            const float v13 = Vb[(size_t)(t + 3) * HIDDEN + h1];
#pragma unroll
            for (int r = 0; r < TM; r++) {
                const float4 av = s_s4[r * 128 + t4];   // broadcast
                o0[r] += av.x * v00 + av.y * v01 + av.z * v02 + av.w * v03;
                o1[r] += av.x * v10 + av.y * v11 + av.z * v12 + av.w * v13;
            }
        }
#pragma unroll
        for (int r = 0; r < TM; r++) {
            out[((size_t)(b * ALEN + a0 + r)) * HIDDEN + h0] = o0[r];
            out[((size_t)(b * ALEN + a0 + r)) * HIDDEN + h1] = o1[r];
        }
    }
}

// ---------------------------------------------------------------------------
extern "C" void kernel_launch(void* const* d_in, const int* in_sizes, int n_in,
                              void* d_out, int out_size, void* d_ws, size_t ws_size,
                              hipStream_t stream)
{
    const float* audio = (const float*)d_in[0];   // [8,2048,512]
    const float* text  = (const float*)d_in[1];   // [8,512,768]
    const float* Wq    = (const float*)d_in[2];   // [512,512]
    const float* bq    = (const float*)d_in[3];   // [512]
    const float* Wk    = (const float*)d_in[4];   // [768,512]
    const float* bk    = (const float*)d_in[5];   // [512]
    const float* Wv    = (const float*)d_in[6];   // [768,512]
    const float* bv    = (const float*)d_in[7];   // [512]
    const int*   mask  = (const int*)d_in[8];     // [8,512]
    float* out = (float*)d_out;

    float* Kbuf = (float*)d_ws;                                   // 8.4 MB
    float* Vbuf = Kbuf + (size_t)BATCH * TLEN * HIDDEN;           // 8.4 MB

    // Q = audio @ Wq + bq  -> stored in d_out (scratch; fully overwritten later)
    gemm_bias_kernel<<<dim3(HIDDEN / BN, (BATCH * ALEN) / BM), 256, 0, stream>>>(
        audio, Wq, bq, out, BATCH * ALEN, HIDDEN, AUDIO_DIM);
    // K = text @ Wk + bk
    gemm_bias_kernel<<<dim3(HIDDEN / BN, (BATCH * TLEN) / BM), 256, 0, stream>>>(
        text, Wk, bk, Kbuf, BATCH * TLEN, HIDDEN, TEXT_DIM);
    // V = text @ Wv + bv
    gemm_bias_kernel<<<dim3(HIDDEN / BN, (BATCH * TLEN) / BM), 256, 0, stream>>>(
        text, Wv, bv, Vbuf, BATCH * TLEN, HIDDEN, TEXT_DIM);
    // Fused scores/softmax/PV
    attn_kernel<<<dim3(ALEN / TM, BATCH), 256, 0, stream>>>(Kbuf, Vbuf, mask, out);
}

// Round 2
// 215.828 us; speedup vs baseline: 3.4897x; 3.4897x over previous
//
#include <hip/hip_runtime.h>
#include <cstdint>
#include <cstddef>

#define AUDIO_DIM 512
#define TEXT_DIM  768
#define HIDDEN    512
#define BATCH     8
#define ALEN      2048
#define TLEN      512

typedef _Float16 half8 __attribute__((ext_vector_type(8)));
typedef _Float16 half4_t __attribute__((ext_vector_type(4)));
typedef float floatx4 __attribute__((ext_vector_type(4)));

#define AS1 __attribute__((address_space(1)))
#define AS3 __attribute__((address_space(3)))

// Async global->LDS, 16B per lane. LDS dest = wave-uniform base + lane*16.
__device__ __forceinline__ void gload_lds16(const void* g, void* l) {
    __builtin_amdgcn_global_load_lds((const AS1 void*)g, (AS3 void*)l, 16, 0, 0);
}

// XOR swizzle: 16B chunk c of row r lives at slot c ^ g(r); makes the
// 64B-row fragment reads 2-way bank aliasing (free) instead of 8-way.
__device__ __forceinline__ int swz(int r) { return (r >> 1) & 3; }

// ---------------------------------------------------------------------------
// fp32 -> fp16 elementwise convert (vectorized)
// ---------------------------------------------------------------------------
__global__ __launch_bounds__(256) void conv_f32_f16(const float* __restrict__ src,
                                                    _Float16* __restrict__ dst, int n4) {
    int i = blockIdx.x * 256 + threadIdx.x;
    if (i >= n4) return;
    float4 v = ((const float4*)src)[i];
    half4_t h;
    h.x = (_Float16)v.x; h.y = (_Float16)v.y; h.z = (_Float16)v.z; h.w = (_Float16)v.w;
    ((half4_t*)dst)[i] = h;
}

// ---------------------------------------------------------------------------
// Transpose (+convert to fp16): dst[c][r] = (f16)src[r][c]. src is [R][C].
// Batched via grid.z. 32x32 LDS tile.
// ---------------------------------------------------------------------------
template <typename T>
__global__ __launch_bounds__(256) void trans_to_f16(const T* __restrict__ src,
                                                    _Float16* __restrict__ dst,
                                                    int R, int C, long sb, long db) {
    __shared__ _Float16 t[32][33];
    src += (size_t)blockIdx.z * sb;
    dst += (size_t)blockIdx.z * db;
    const int c0 = blockIdx.x * 32, r0 = blockIdx.y * 32;
    const int tx = threadIdx.x & 31, ty = threadIdx.x >> 5;   // 32x8
#pragma unroll
    for (int i = 0; i < 4; i++) {
        int r = ty + i * 8;
        t[r][tx] = (_Float16)src[(size_t)(r0 + r) * C + c0 + tx];
    }
    __syncthreads();
#pragma unroll
    for (int i = 0; i < 4; i++) {
        int r = ty + i * 8;
        dst[(size_t)(c0 + r) * R + r0 + tx] = t[tx][r];
    }
}

// ---------------------------------------------------------------------------
// f16 MFMA GEMM: C[M,N] = A[M,K] @ Bt[N,K]^T (+ bias). 128x128 tile, BK=32,
// 256 threads / 4 waves, each wave 64x64 via 4x4 MFMA tiles of 16x16x32.
// OUT16: C is f16 with fp32 bias add; else C is fp32, no bias.
// Batched via grid.z with element strides As_/Bs_/Cs_.
// ---------------------------------------------------------------------------
template <bool OUT16>
__global__ __launch_bounds__(256, 2) void gemm16(
    const _Float16* __restrict__ A, const _Float16* __restrict__ Bt,
    const float* __restrict__ bias, void* __restrict__ Cp,
    int M, int N, int K, long As_, long Bs_, long Cs_) {
    __shared__ __align__(16) _Float16 Asm[128 * 32];   // [r][k] 64B rows, swizzled
    __shared__ __align__(16) _Float16 Bsm[128 * 32];
    const int tid = threadIdx.x;
    const int l = tid & 63, w = tid >> 6;
    const int m0 = blockIdx.y * 128, n0 = blockIdx.x * 128;
    A  += (size_t)blockIdx.z * As_;
    Bt += (size_t)blockIdx.z * Bs_;
    const int wm = w >> 1, wn = w & 1;
    const int srow = l >> 2, sj = l & 3;       // staging: lane -> (row, chunk-slot)
    const int q = l >> 4, c16 = l & 15;        // MFMA lane coords

    floatx4 acc[4][4] = {};

    for (int k0 = 0; k0 < K; k0 += 32) {
        if (k0) __syncthreads();
#pragma unroll
        for (int i = 0; i < 2; i++) {
            int rb = (w * 2 + i) * 16;
            int r = rb + srow;
            int cc = sj ^ swz(r);
            gload_lds16(A + (size_t)(m0 + r) * K + k0 + cc * 8, &Asm[rb * 32]);
            gload_lds16(Bt + (size_t)(n0 + r) * K + k0 + cc * 8, &Bsm[rb * 32]);
        }
        __syncthreads();

        half8 af[4], bf[4];
#pragma unroll
        for (int t = 0; t < 4; t++) {
            int rA = wm * 64 + t * 16 + c16;
            af[t] = *(const half8*)&Asm[rA * 32 + ((q ^ swz(rA)) << 3)];
            int rB = wn * 64 + t * 16 + c16;
            bf[t] = *(const half8*)&Bsm[rB * 32 + ((q ^ swz(rB)) << 3)];
        }
#pragma unroll
        for (int mi = 0; mi < 4; mi++)
#pragma unroll
            for (int ni = 0; ni < 4; ni++)
                acc[mi][ni] = __builtin_amdgcn_mfma_f32_16x16x32_f16(
                    af[mi], bf[ni], acc[mi][ni], 0, 0, 0);
    }

    // Epilogue. C/D layout: col = c16, row = q*4 + reg (per 16x16 tile).
    if (OUT16) {
        _Float16* C = (_Float16*)Cp + (size_t)blockIdx.z * Cs_;
#pragma unroll
        for (int ni = 0; ni < 4; ni++) {
            int col = n0 + wn * 64 + ni * 16 + c16;
            float bv = bias[col];
#pragma unroll
            for (int mi = 0; mi < 4; mi++) {
                int row = m0 + wm * 64 + mi * 16 + q * 4;
#pragma unroll
                for (int r = 0; r < 4; r++)
                    C[(size_t)(row + r) * N + col] = (_Float16)(acc[mi][ni][r] + bv);
            }
        }
    } else {
        float* C = (float*)Cp + (size_t)blockIdx.z * Cs_;
#pragma unroll
        for (int ni = 0; ni < 4; ni++) {
            int col = n0 + wn * 64 + ni * 16 + c16;
#pragma unroll
            for (int mi = 0; mi < 4; mi++) {
                int row = m0 + wm * 64 + mi * 16 + q * 4;
#pragma unroll
                for (int r = 0; r < 4; r++)
                    C[(size_t)(row + r) * N + col] = acc[mi][ni][r];
            }
        }
    }
}

// ---------------------------------------------------------------------------
// Fused scores + softmax: per block = (batch, 64 audio rows) x all 512 keys.
// S = (Q @ K^T) * scale, masked; row softmax (cross-wave LDS reduce);
// P written as f16. Wave w owns cols [w*128, w*128+128), all 64 rows.
// ---------------------------------------------------------------------------
__global__ __launch_bounds__(256, 2) void scores_softmax(
    const _Float16* __restrict__ Qh, const _Float16* __restrict__ Kh,
    const int* __restrict__ mask, _Float16* __restrict__ P) {
    __shared__ __align__(16) _Float16 Qs[64 * 32];    // 4 KB
    __shared__ __align__(16) _Float16 Ks[512 * 32];   // 32 KB
    __shared__ float red[4][64];
    __shared__ float red2[4][64];
    const int tid = threadIdx.x, l = tid & 63, w = tid >> 6;
    const int b = blockIdx.y, a0 = blockIdx.x * 64;
    const _Float16* Qb = Qh + (size_t)(b * ALEN + a0) * HIDDEN;
    const _Float16* Kb = Kh + (size_t)b * TLEN * HIDDEN;
    const int srow = l >> 2, sj = l & 3;
    const int q = l >> 4, c16 = l & 15;

    floatx4 acc[4][8] = {};

    for (int k0 = 0; k0 < HIDDEN; k0 += 32) {
        if (k0) __syncthreads();
        {   // Q tile: 1 issue/wave
            int rb = w * 16;
            int r = rb + srow;
            int cc = sj ^ swz(r);
            gload_lds16(Qb + (size_t)r * HIDDEN + k0 + cc * 8, &Qs[rb * 32]);
        }
#pragma unroll
        for (int i = 0; i < 8; i++) {   // K tile: 8 issues/wave
            int rb = (w * 8 + i) * 16;
            int r = rb + srow;
            int cc = sj ^ swz(r);
            gload_lds16(Kb + (size_t)r * HIDDEN + k0 + cc * 8, &Ks[rb * 32]);
        }
        __syncthreads();

        half8 af[4], bf[8];
#pragma unroll
        for (int t = 0; t < 4; t++) {
            int rA = t * 16 + c16;
            af[t] = *(const half8*)&Qs[rA * 32 + ((q ^ swz(rA)) << 3)];
        }
#pragma unroll
        for (int t = 0; t < 8; t++) {
            int rB = w * 128 + t * 16 + c16;
            bf[t] = *(const half8*)&Ks[rB * 32 + ((q ^ swz(rB)) << 3)];
        }
#pragma unroll
        for (int mi = 0; mi < 4; mi++)
#pragma unroll
            for (int ni = 0; ni < 8; ni++)
                acc[mi][ni] = __builtin_amdgcn_mfma_f32_16x16x32_f16(
                    af[mi], bf[ni], acc[mi][ni], 0, 0, 0);
    }

    const float scale = 0.044194173824159216f;   // 512^-0.5
    int mv[8];
#pragma unroll
    for (int ni = 0; ni < 8; ni++)
        mv[ni] = mask[b * TLEN + w * 128 + ni * 16 + c16];
#pragma unroll
    for (int mi = 0; mi < 4; mi++)
#pragma unroll
        for (int ni = 0; ni < 8; ni++)
#pragma unroll
            for (int r = 0; r < 4; r++)
                acc[mi][ni][r] = mv[ni] ? acc[mi][ni][r] * scale : -1e30f;

    // row max: in-lane over 8 n-tiles, shuffle over the 16 col-lanes, LDS over waves
    float mx[4][4];
#pragma unroll
    for (int mi = 0; mi < 4; mi++)
#pragma unroll
        for (int r = 0; r < 4; r++) {
            float m = -1e30f;
#pragma unroll
            for (int ni = 0; ni < 8; ni++) m = fmaxf(m, acc[mi][ni][r]);
#pragma unroll
            for (int off = 1; off <= 8; off <<= 1) m = fmaxf(m, __shfl_xor(m, off));
            mx[mi][r] = m;
        }
    if (c16 == 0)
#pragma unroll
        for (int mi = 0; mi < 4; mi++)
#pragma unroll
            for (int r = 0; r < 4; r++) red[w][mi * 16 + q * 4 + r] = mx[mi][r];
    __syncthreads();
#pragma unroll
    for (int mi = 0; mi < 4; mi++)
#pragma unroll
        for (int r = 0; r < 4; r++) {
            int row = mi * 16 + q * 4 + r;
            mx[mi][r] = fmaxf(fmaxf(red[0][row], red[1][row]),
                              fmaxf(red[2][row], red[3][row]));
        }

    // exp + row sum
    float sm[4][4];
#pragma unroll
    for (int mi = 0; mi < 4; mi++)
#pragma unroll
        for (int r = 0; r < 4; r++) {
            float s = 0.f;
#pragma unroll
            for (int ni = 0; ni < 8; ni++) {
                float e = __expf(acc[mi][ni][r] - mx[mi][r]);
                acc[mi][ni][r] = e;
                s += e;
            }
#pragma unroll
            for (int off = 1; off <= 8; off <<= 1) s += __shfl_xor(s, off);
            sm[mi][r] = s;
        }
    if (c16 == 0)
#pragma unroll
        for (int mi = 0; mi < 4; mi++)
#pragma unroll
            for (int r = 0; r < 4; r++) red2[w][mi * 16 + q * 4 + r] = sm[mi][r];
    __syncthreads();

    _Float16* Pb = P + (size_t)(b * ALEN + a0) * TLEN;
#pragma unroll
    for (int mi = 0; mi < 4; mi++)
#pragma unroll
        for (int r = 0; r < 4; r++) {
            int row = mi * 16 + q * 4 + r;
            float inv = 1.f / (red2[0][row] + red2[1][row] + red2[2][row] + red2[3][row]);
#pragma unroll
            for (int ni = 0; ni < 8; ni++)
                Pb[(size_t)row * TLEN + w * 128 + ni * 16 + c16] =
                    (_Float16)(acc[mi][ni][r] * inv);
        }
}

// ---------------------------------------------------------------------------
extern "C" void kernel_launch(void* const* d_in, const int* in_sizes, int n_in,
                              void* d_out, int out_size, void* d_ws, size_t ws_size,
                              hipStream_t stream)
{
    const float* audio = (const float*)d_in[0];   // [8,2048,512]
    const float* text  = (const float*)d_in[1];   // [8,512,768]
    const float* Wq    = (const float*)d_in[2];   // [512,512]
    const float* bq    = (const float*)d_in[3];
    const float* Wk    = (const float*)d_in[4];   // [768,512]
    const float* bk    = (const float*)d_in[5];
    const float* Wv    = (const float*)d_in[6];   // [768,512]
    const float* bv    = (const float*)d_in[7];
    const int*   maskp = (const int*)d_in[8];     // [8,512]
    float* out = (float*)d_out;

    // d_out doubles as f16 scratch until the final PV GEMM overwrites it:
    //   [0 .. 8.39M) halfs: audio_h ; [8.39M .. 16.78M): Qh   (exactly 33.5 MB)
    _Float16* audio_h = (_Float16*)d_out;
    _Float16* Qh      = audio_h + (size_t)8388608;

    // ws layout (halfs), total ~37.7 MB
    _Float16* ws16   = (_Float16*)d_ws;
    _Float16* text_h = ws16;                        // 3,145,728
    _Float16* Wq_t   = text_h + 3145728;            //   262,144  [512][512]
    _Float16* Wk_t   = Wq_t + 262144;               //   393,216  [512][768]
    _Float16* Wv_t   = Wk_t + 393216;               //   393,216  [512][768]
    _Float16* Kh     = Wv_t + 393216;               // 2,097,152  [B,512,512]
    _Float16* Vh     = Kh + 2097152;                // 2,097,152
    _Float16* Vt     = Vh + 2097152;                // 2,097,152  [B,512(h),512(t)]
    _Float16* P      = Vt + 2097152;                // 8,388,608  [B,2048,512]

    // 1) convert inputs to f16
    conv_f32_f16<<<8192, 256, 0, stream>>>(audio, audio_h, 2097152);
    conv_f32_f16<<<3072, 256, 0, stream>>>(text, text_h, 786432);
    trans_to_f16<float><<<dim3(16, 16, 1), 256, 0, stream>>>(Wq, Wq_t, 512, 512, 0, 0);
    trans_to_f16<float><<<dim3(16, 24, 1), 256, 0, stream>>>(Wk, Wk_t, 768, 512, 0, 0);
    trans_to_f16<float><<<dim3(16, 24, 1), 256, 0, stream>>>(Wv, Wv_t, 768, 512, 0, 0);

    // 2) Q/K/V GEMMs (f16 out)
    gemm16<true><<<dim3(4, 128, 1), 256, 0, stream>>>(
        audio_h, Wq_t, bq, Qh, 16384, 512, 512, 0, 0, 0);
    gemm16<true><<<dim3(4, 32, 1), 256, 0, stream>>>(
        text_h, Wk_t, bk, Kh, 4096, 512, 768, 0, 0, 0);
    gemm16<true><<<dim3(4, 32, 1), 256, 0, stream>>>(
        text_h, Wv_t, bv, Vh, 4096, 512, 768, 0, 0, 0);

    // 3) V -> V^T per batch (B-operand layout for PV)
    trans_to_f16<_Float16><<<dim3(16, 16, 8), 256, 0, stream>>>(
        Vh, Vt, 512, 512, 262144, 262144);

    // 4) fused scores + softmax -> P (f16)
    scores_softmax<<<dim3(32, 8), 256, 0, stream>>>(Qh, Kh, maskp, P);

    // 5) out = P @ V  (fp32 out, batched)
    gemm16<false><<<dim3(4, 16, 8), 256, 0, stream>>>(
        P, Vt, nullptr, out, 2048, 512, 512, 1048576, 262144, 1048576);
}

// Round 3
// 177.068 us; speedup vs baseline: 4.2536x; 1.2189x over previous
//
#include <hip/hip_runtime.h>
#include <cstdint>
#include <cstddef>

#define AUDIO_DIM 512
#define TEXT_DIM  768
#define HIDDEN    512
#define BATCH     8
#define ALEN      2048
#define TLEN      512

typedef _Float16 half8 __attribute__((ext_vector_type(8)));
typedef _Float16 half4_t __attribute__((ext_vector_type(4)));
typedef float floatx4 __attribute__((ext_vector_type(4)));

#define AS1 __attribute__((address_space(1)))
#define AS3 __attribute__((address_space(3)))

// Async global->LDS, 16B per lane. LDS dest = wave-uniform base + lane*16.
__device__ __forceinline__ void gload_lds16(const void* g, void* l) {
    __builtin_amdgcn_global_load_lds((const AS1 void*)g, (AS3 void*)l, 16, 0, 0);
}

// XOR swizzle: 16B chunk c of row r lives at slot c ^ swz(r); makes the
// 64B-row fragment reads 2-way bank aliasing (free) instead of 8-way.
__device__ __forceinline__ int swz(int r) { return (r >> 1) & 3; }

// ---------------------------------------------------------------------------
// prep: ONE kernel for all input conditioning (was 5 dispatches).
//   blocks [0,8192)      : audio fp32 -> f16 (float4-vectorized)
//   blocks [8192,11264)  : text  fp32 -> f16
//   blocks [11264,11520) : Wq [512][512] -> Wq_t [512][512] f16 (transpose)
//   blocks [11520,11904) : Wk [768][512] -> Wk_t [512][768] f16
//   blocks [11904,12288) : Wv [768][512] -> Wv_t [512][768] f16
// ---------------------------------------------------------------------------
__global__ __launch_bounds__(256) void prep(
    const float* __restrict__ audio, const float* __restrict__ text,
    const float* __restrict__ Wq, const float* __restrict__ Wk,
    const float* __restrict__ Wv,
    _Float16* __restrict__ audio_h, _Float16* __restrict__ text_h,
    _Float16* __restrict__ Wq_t, _Float16* __restrict__ Wk_t,
    _Float16* __restrict__ Wv_t)
{
    __shared__ _Float16 tt[32 * 33];
    const int bid = blockIdx.x, tid = threadIdx.x;
    if (bid < 11264) {
        const float* src; _Float16* dst; int i;
        if (bid < 8192) { src = audio; dst = audio_h; i = bid * 256 + tid; }
        else            { src = text;  dst = text_h;  i = (bid - 8192) * 256 + tid; }
        float4 v = ((const float4*)src)[i];
        half4_t h;
        h.x = (_Float16)v.x; h.y = (_Float16)v.y; h.z = (_Float16)v.z; h.w = (_Float16)v.w;
        ((half4_t*)dst)[i] = h;
    } else {
        const float* src; _Float16* dst; int R, lb;
        if (bid < 11520)      { lb = bid - 11264; src = Wq; dst = Wq_t; R = 512; }
        else if (bid < 11904) { lb = bid - 11520; src = Wk; dst = Wk_t; R = 768; }
        else                  { lb = bid - 11904; src = Wv; dst = Wv_t; R = 768; }
        const int C = 512;
        const int c0 = (lb & 15) * 32, r0 = (lb >> 4) * 32;
        const int tx = tid & 31, ty = tid >> 5;   // 32 x 8
#pragma unroll
        for (int i = 0; i < 4; i++) {
            int r = ty + i * 8;
            tt[r * 33 + tx] = (_Float16)src[(size_t)(r0 + r) * C + c0 + tx];
        }
        __syncthreads();
#pragma unroll
        for (int i = 0; i < 4; i++) {
            int r = ty + i * 8;
            dst[(size_t)(c0 + r) * R + r0 + tx] = tt[tx * 33 + r];
        }
    }
}

// ---------------------------------------------------------------------------
// Shared f16 MFMA GEMM body: C[.,N] tile at (m0,n0) = A[M,K] @ Bt[N,K]^T.
// 128x128 tile, BK=32, 256 threads / 4 waves, wave = 64x64 via 4x4 MFMA
// tiles of 16x16x32. OUT16: f16 out + bias; ROWBIAS: bias indexed by row.
// ---------------------------------------------------------------------------
template <bool OUT16, bool ROWBIAS>
__device__ __forceinline__ void gemm_body(
    const _Float16* __restrict__ A, const _Float16* __restrict__ Bt,
    const float* __restrict__ bias, void* __restrict__ Cp,
    int N, int K, int m0, int n0, _Float16* Asm, _Float16* Bsm)
{
    const int tid = threadIdx.x;
    const int l = tid & 63, w = tid >> 6;
    const int wm = w >> 1, wn = w & 1;
    const int srow = l >> 2, sj = l & 3;       // staging: lane -> (row, chunk-slot)
    const int q = l >> 4, c16 = l & 15;        // MFMA lane coords

    floatx4 acc[4][4] = {};

    for (int k0 = 0; k0 < K; k0 += 32) {
        if (k0) __syncthreads();
#pragma unroll
        for (int i = 0; i < 2; i++) {
            int rb = (w * 2 + i) * 16;
            int r = rb + srow;
            int cc = sj ^ swz(r);
            gload_lds16(A + (size_t)(m0 + r) * K + k0 + cc * 8, Asm + rb * 32);
            gload_lds16(Bt + (size_t)(n0 + r) * K + k0 + cc * 8, Bsm + rb * 32);
        }
        __syncthreads();

        half8 af[4], bf[4];
#pragma unroll
        for (int t = 0; t < 4; t++) {
            int rA = wm * 64 + t * 16 + c16;
            af[t] = *(const half8*)&Asm[rA * 32 + ((q ^ swz(rA)) << 3)];
            int rB = wn * 64 + t * 16 + c16;
            bf[t] = *(const half8*)&Bsm[rB * 32 + ((q ^ swz(rB)) << 3)];
        }
#pragma unroll
        for (int mi = 0; mi < 4; mi++)
#pragma unroll
            for (int ni = 0; ni < 4; ni++)
                acc[mi][ni] = __builtin_amdgcn_mfma_f32_16x16x32_f16(
                    af[mi], bf[ni], acc[mi][ni], 0, 0, 0);
    }

    // Epilogue. C/D layout per 16x16 tile: col = c16, row = q*4 + reg.
    if (OUT16) {
        float bcol[4];
        float brow[4][4];
        if (!ROWBIAS) {
#pragma unroll
            for (int ni = 0; ni < 4; ni++)
                bcol[ni] = bias[n0 + wn * 64 + ni * 16 + c16];
        } else {
#pragma unroll
            for (int mi = 0; mi < 4; mi++) {
                float4 b4 = *(const float4*)&bias[m0 + wm * 64 + mi * 16 + q * 4];
                brow[mi][0] = b4.x; brow[mi][1] = b4.y;
                brow[mi][2] = b4.z; brow[mi][3] = b4.w;
            }
        }
        _Float16* C = (_Float16*)Cp;
#pragma unroll
        for (int ni = 0; ni < 4; ni++) {
            int col = n0 + wn * 64 + ni * 16 + c16;
#pragma unroll
            for (int mi = 0; mi < 4; mi++) {
                int row = m0 + wm * 64 + mi * 16 + q * 4;
#pragma unroll
                for (int r = 0; r < 4; r++) {
                    float b = ROWBIAS ? brow[mi][r] : bcol[ni];
                    C[(size_t)(row + r) * N + col] = (_Float16)(acc[mi][ni][r] + b);
                }
            }
        }
    } else {
        float* C = (float*)Cp;
#pragma unroll
        for (int ni = 0; ni < 4; ni++) {
            int col = n0 + wn * 64 + ni * 16 + c16;
#pragma unroll
            for (int mi = 0; mi < 4; mi++) {
                int row = m0 + wm * 64 + mi * 16 + q * 4;
#pragma unroll
                for (int r = 0; r < 4; r++)
                    C[(size_t)(row + r) * N + col] = acc[mi][ni][r];
            }
        }
    }
}

// ---------------------------------------------------------------------------
// qkv_gemm: ONE kernel, 768 blocks (3/CU), demuxed:
//   [0,512)   Q  = audio_h[16384,512] @ Wq_t^T + bq      -> Qh f16
//   [512,640) K  = text_h[4096,768]  @ Wk_t^T + bk       -> Kh f16
//   [640,768) V^T[h][t] = Wv_t[512,768] @ text_h(b)^T + bv[h] -> Vt f16 (batched)
// The V GEMM emits V already transposed (B-operand layout for PV) --
// eliminates the separate transpose kernel.
// ---------------------------------------------------------------------------
__global__ __launch_bounds__(256, 2) void qkv_gemm(
    const _Float16* __restrict__ audio_h, const _Float16* __restrict__ text_h,
    const _Float16* __restrict__ Wq_t, const _Float16* __restrict__ Wk_t,
    const _Float16* __restrict__ Wv_t,
    const float* __restrict__ bq, const float* __restrict__ bk,
    const float* __restrict__ bv,
    _Float16* __restrict__ Qh, _Float16* __restrict__ Kh,
    _Float16* __restrict__ Vt)
{
    __shared__ __align__(16) _Float16 Asm[128 * 32];
    __shared__ __align__(16) _Float16 Bsm[128 * 32];
    const int bid = blockIdx.x;
    if (bid < 512) {
        gemm_body<true, false>(audio_h, Wq_t, bq, Qh, 512, 512,
                               (bid >> 2) * 128, (bid & 3) * 128, Asm, Bsm);
    } else if (bid < 640) {
        int lb = bid - 512;
        gemm_body<true, false>(text_h, Wk_t, bk, Kh, 512, 768,
                               (lb >> 2) * 128, (lb & 3) * 128, Asm, Bsm);
    } else {
        int lb = bid - 640;
        int z = lb >> 4, by = (lb >> 2) & 3, bx = lb & 3;
        gemm_body<true, true>(Wv_t, text_h + (size_t)z * 393216, bv,
                              Vt + (size_t)z * 262144, 512, 768,
                              by * 128, bx * 128, Asm, Bsm);
    }
}

// ---------------------------------------------------------------------------
// pv_gemm: out = P @ V (fp32 out), batched over grid.z.
// ---------------------------------------------------------------------------
__global__ __launch_bounds__(256, 2) void pv_gemm(
    const _Float16* __restrict__ P, const _Float16* __restrict__ Vt,
    float* __restrict__ out)
{
    __shared__ __align__(16) _Float16 Asm[128 * 32];
    __shared__ __align__(16) _Float16 Bsm[128 * 32];
    const int z = blockIdx.z;
    gemm_body<false, false>(P + (size_t)z * 1048576, Vt + (size_t)z * 262144,
                            nullptr, out + (size_t)z * 1048576, 512, 512,
                            blockIdx.y * 128, blockIdx.x * 128, Asm, Bsm);
}

// ---------------------------------------------------------------------------
// Fused scores + softmax: per block = (batch, 64 audio rows) x all 512 keys.
// S = (Q @ K^T) * scale, masked; row softmax (cross-wave LDS reduce);
// P written as f16. Wave w owns cols [w*128, w*128+128), all 64 rows.
// ---------------------------------------------------------------------------
__global__ __launch_bounds__(256, 2) void scores_softmax(
    const _Float16* __restrict__ Qh, const _Float16* __restrict__ Kh,
    const int* __restrict__ mask, _Float16* __restrict__ P) {
    __shared__ __align__(16) _Float16 Qs[64 * 32];    // 4 KB
    __shared__ __align__(16) _Float16 Ks[512 * 32];   // 32 KB
    __shared__ float red[4][64];
    __shared__ float red2[4][64];
    const int tid = threadIdx.x, l = tid & 63, w = tid >> 6;
    const int b = blockIdx.y, a0 = blockIdx.x * 64;
    const _Float16* Qb = Qh + (size_t)(b * ALEN + a0) * HIDDEN;
    const _Float16* Kb = Kh + (size_t)b * TLEN * HIDDEN;
    const int srow = l >> 2, sj = l & 3;
    const int q = l >> 4, c16 = l & 15;

    floatx4 acc[4][8] = {};

    for (int k0 = 0; k0 < HIDDEN; k0 += 32) {
        if (k0) __syncthreads();
        {   // Q tile: 1 issue/wave
            int rb = w * 16;
            int r = rb + srow;
            int cc = sj ^ swz(r);
            gload_lds16(Qb + (size_t)r * HIDDEN + k0 + cc * 8, &Qs[rb * 32]);
        }
#pragma unroll
        for (int i = 0; i < 8; i++) {   // K tile: 8 issues/wave
            int rb = (w * 8 + i) * 16;
            int r = rb + srow;
            int cc = sj ^ swz(r);
            gload_lds16(Kb + (size_t)r * HIDDEN + k0 + cc * 8, &Ks[rb * 32]);
        }
        __syncthreads();

        half8 af[4], bf[8];
#pragma unroll
        for (int t = 0; t < 4; t++) {
            int rA = t * 16 + c16;
            af[t] = *(const half8*)&Qs[rA * 32 + ((q ^ swz(rA)) << 3)];
        }
#pragma unroll
        for (int t = 0; t < 8; t++) {
            int rB = w * 128 + t * 16 + c16;
            bf[t] = *(const half8*)&Ks[rB * 32 + ((q ^ swz(rB)) << 3)];
        }
#pragma unroll
        for (int mi = 0; mi < 4; mi++)
#pragma unroll
            for (int ni = 0; ni < 8; ni++)
                acc[mi][ni] = __builtin_amdgcn_mfma_f32_16x16x32_f16(
                    af[mi], bf[ni], acc[mi][ni], 0, 0, 0);
    }

    const float scale = 0.044194173824159216f;   // 512^-0.5
    int mv[8];
#pragma unroll
    for (int ni = 0; ni < 8; ni++)
        mv[ni] = mask[b * TLEN + w * 128 + ni * 16 + c16];
#pragma unroll
    for (int mi = 0; mi < 4; mi++)
#pragma unroll
        for (int ni = 0; ni < 8; ni++)
#pragma unroll
            for (int r = 0; r < 4; r++)
                acc[mi][ni][r] = mv[ni] ? acc[mi][ni][r] * scale : -1e30f;

    // row max: in-lane over 8 n-tiles, shuffle over the 16 col-lanes, LDS over waves
    float mx[4][4];
#pragma unroll
    for (int mi = 0; mi < 4; mi++)
#pragma unroll
        for (int r = 0; r < 4; r++) {
            float m = -1e30f;
#pragma unroll
            for (int ni = 0; ni < 8; ni++) m = fmaxf(m, acc[mi][ni][r]);
#pragma unroll
            for (int off = 1; off <= 8; off <<= 1) m = fmaxf(m, __shfl_xor(m, off));
            mx[mi][r] = m;
        }
    if (c16 == 0)
#pragma unroll
        for (int mi = 0; mi < 4; mi++)
#pragma unroll
            for (int r = 0; r < 4; r++) red[w][mi * 16 + q * 4 + r] = mx[mi][r];
    __syncthreads();
#pragma unroll
    for (int mi = 0; mi < 4; mi++)
#pragma unroll
        for (int r = 0; r < 4; r++) {
            int row = mi * 16 + q * 4 + r;
            mx[mi][r] = fmaxf(fmaxf(red[0][row], red[1][row]),
                              fmaxf(red[2][row], red[3][row]));
        }

    // exp + row sum
    float sm[4][4];
#pragma unroll
    for (int mi = 0; mi < 4; mi++)
#pragma unroll
        for (int r = 0; r < 4; r++) {
            float s = 0.f;
#pragma unroll
            for (int ni = 0; ni < 8; ni++) {
                float e = __expf(acc[mi][ni][r] - mx[mi][r]);
                acc[mi][ni][r] = e;
                s += e;
            }
#pragma unroll
            for (int off = 1; off <= 8; off <<= 1) s += __shfl_xor(s, off);
            sm[mi][r] = s;
        }
    if (c16 == 0)
#pragma unroll
        for (int mi = 0; mi < 4; mi++)
#pragma unroll
            for (int r = 0; r < 4; r++) red2[w][mi * 16 + q * 4 + r] = sm[mi][r];
    __syncthreads();

    _Float16* Pb = P + (size_t)(b * ALEN + a0) * TLEN;
#pragma unroll
    for (int mi = 0; mi < 4; mi++)
#pragma unroll
        for (int r = 0; r < 4; r++) {
            int row = mi * 16 + q * 4 + r;
            float inv = 1.f / (red2[0][row] + red2[1][row] + red2[2][row] + red2[3][row]);
#pragma unroll
            for (int ni = 0; ni < 8; ni++)
                Pb[(size_t)row * TLEN + w * 128 + ni * 16 + c16] =
                    (_Float16)(acc[mi][ni][r] * inv);
        }
}

// ---------------------------------------------------------------------------
extern "C" void kernel_launch(void* const* d_in, const int* in_sizes, int n_in,
                              void* d_out, int out_size, void* d_ws, size_t ws_size,
                              hipStream_t stream)
{
    const float* audio = (const float*)d_in[0];   // [8,2048,512]
    const float* text  = (const float*)d_in[1];   // [8,512,768]
    const float* Wq    = (const float*)d_in[2];   // [512,512]
    const float* bq    = (const float*)d_in[3];
    const float* Wk    = (const float*)d_in[4];   // [768,512]
    const float* bk    = (const float*)d_in[5];
    const float* Wv    = (const float*)d_in[6];   // [768,512]
    const float* bv    = (const float*)d_in[7];
    const int*   maskp = (const int*)d_in[8];     // [8,512]
    float* out = (float*)d_out;

    // d_out doubles as f16 scratch until pv_gemm overwrites it:
    //   [0 .. 8.39M) halfs: audio_h ; [8.39M .. 16.78M): Qh (= 33.5 MB exactly)
    _Float16* audio_h = (_Float16*)d_out;
    _Float16* Qh      = audio_h + (size_t)8388608;

    // ws layout (halfs)
    _Float16* ws16   = (_Float16*)d_ws;
    _Float16* text_h = ws16;                        // 3,145,728  [B*512][768]
    _Float16* Wq_t   = text_h + 3145728;            //   262,144  [512][512]
    _Float16* Wk_t   = Wq_t + 262144;               //   393,216  [512][768]
    _Float16* Wv_t   = Wk_t + 393216;               //   393,216  [512][768]
    _Float16* Kh     = Wv_t + 393216;               // 2,097,152  [B,512,512]
    _Float16* Vt     = Kh + 2097152;                // 2,097,152  [B,512(h),512(t)]
    _Float16* P      = Vt + 2097152;                // 8,388,608  [B,2048,512]

    // 1) all input conditioning in one dispatch
    prep<<<12288, 256, 0, stream>>>(audio, text, Wq, Wk, Wv,
                                    audio_h, text_h, Wq_t, Wk_t, Wv_t);
    // 2) Q + K + V^T GEMMs in one dispatch (768 blocks = 3/CU)
    qkv_gemm<<<768, 256, 0, stream>>>(audio_h, text_h, Wq_t, Wk_t, Wv_t,
                                      bq, bk, bv, Qh, Kh, Vt);
    // 3) fused scores + softmax -> P (f16)
    scores_softmax<<<dim3(32, 8), 256, 0, stream>>>(Qh, Kh, maskp, P);
    // 4) out = P @ V (fp32, batched)
    pv_gemm<<<dim3(4, 16, 8), 256, 0, stream>>>(P, Vt, out);
}